// Round 8
// baseline (311.061 us; speedup 1.0000x reference)
//
#include <hip/hip_runtime.h>
#include <hip/hip_fp8.h>
#include <stdint.h>

// x(4096x2048) @ W(2048x2048) + bias + probs, tanh.
static constexpr int MM = 4096;
static constexpr int KK = 2048;
static constexpr int NN = 2048;

typedef float floatx16 __attribute__((ext_vector_type(16)));
typedef _Float16 f16x8 __attribute__((ext_vector_type(8)));
typedef unsigned short u16x8 __attribute__((ext_vector_type(8)));
typedef int intx4 __attribute__((ext_vector_type(4)));
typedef int intx8 __attribute__((ext_vector_type(8)));

__device__ __forceinline__ unsigned char f32_to_e4m3(float x) {
  __hip_fp8_e4m3 q(x);           // OCP e4m3fn, RNE + saturate
  return (unsigned char)q.__x;
}
__device__ __forceinline__ float fast_tanh(float x) {
  float e = __expf(2.0f * x);
  return 1.0f - 2.0f / (e + 1.0f);
}
__device__ __forceinline__ unsigned short f32_to_f16_bits(float x) {
  union { _Float16 h; unsigned short u; } c; c.h = (_Float16)x;  // RNE
  return c.u;
}
__device__ __forceinline__ float f16_bits_to_f32(unsigned short u) {
  union { _Float16 h; unsigned short u; } c; c.u = u;
  return (float)c.h;
}

// ---- Layouts (R8: FRAGMENT-MAJOR global, zero-LDS gemm) -------------------
// All planes stored per (32-row tile T, 64-k group g):
//   hi  (fp16):  addr = T*131072 + g*4096 + c8*512 + r*16   (c8 = k/8, 0..7)
//   lo  (e4m3):  addr = T*65536  + g*2048 + c *512 + r*16   (pi-chunk c 0..3)
// lo pi-mapping (UNCHANGED, verified): chunk c, byte b <->
//   k = (c>>1)*32 + (b>>3)*16 + (c&1)*8 + (b&7)
// A wave fragment load (s,t): lanes 0-31 read chunk 2s (rows 0..31), lanes
// 32-63 chunk 2s+1 -> ONE contiguous 1KB transaction.  Same for lo chunks
// {half, 2+half}.  No swizzles needed (no LDS banks, no GLL linearity).

// ---- Fused pre-pass: blocks [0,2048) split x; [2048,3072) split W;
//      [3072,3080) probs+bias.  (values identical; only store ADDRESSES new)
__global__ __launch_bounds__(256) void prepass_kernel(
    const float* __restrict__ x, const float* __restrict__ E,
    const float* __restrict__ W, const float* __restrict__ cb,
    unsigned short* __restrict__ ahi, unsigned char* __restrict__ al8,
    unsigned short* __restrict__ bhi, unsigned char* __restrict__ bl8,
    float* __restrict__ bias2) {
  __shared__ float tile[64][65];
  const int blk = blockIdx.x;
  const int tid = threadIdx.x;

  if (blk < 2048) {
    int idx = blk * 256 + tid;
    int row = idx >> 7;        // 128 units per row
    int u = idx & 127;
    int g = u >> 2;            // 64-k group
    int q = u & 3;             // 16-k quarter within group
    const float4* s = (const float4*)(x + (size_t)row * KK + u * 16);
    float v[16];
#pragma unroll
    for (int p = 0; p < 4; p++) {
      float4 t = s[p];
      v[p * 4 + 0] = t.x; v[p * 4 + 1] = t.y; v[p * 4 + 2] = t.z; v[p * 4 + 3] = t.w;
    }
    unsigned short h[16];
    union { unsigned char b[16]; unsigned long long d[2]; } loq;
#pragma unroll
    for (int e = 0; e < 16; e++) {
      h[e] = f32_to_f16_bits(v[e]);
      float lo = v[e] - f16_bits_to_f32(h[e]);
      loq.b[e] = f32_to_e4m3(lo * 2048.0f);
    }
    char* ah = (char*)ahi + (size_t)(row >> 5) * 131072 + (size_t)g * 4096 + (row & 31) * 16;
#pragma unroll
    for (int cc = 0; cc < 2; cc++) {
      u16x8 o;
#pragma unroll
      for (int e = 0; e < 8; e++) o[e] = h[cc * 8 + e];
      *(u16x8*)(ah + (2 * q + cc) * 512) = o;
    }
    {
      char* al = (char*)al8 + (size_t)(row >> 5) * 65536 + (size_t)g * 2048 +
                 (row & 31) * 16 + (q & 1) * 8;
      *(unsigned long long*)(al + (q & 2) * 512) = loq.d[0];
      *(unsigned long long*)(al + ((q & 2) | 1) * 512) = loq.d[1];
    }
  } else if (blk < 3072) {
    const int wb = blk - 2048;
    const int n0 = (wb & 31) * 64;
    const int k0 = (wb >> 5) * 64;    // one 64-k group
    const int g = wb >> 5;
#pragma unroll
    for (int i = 0; i < 4; i++) {
      int t = tid + i * 256;
      int kr = t >> 4;
      int nc = (t & 15) * 4;
      const float4 vv = *(const float4*)(W + (size_t)(k0 + kr) * NN + n0 + nc);
      tile[nc + 0][kr] = vv.x;
      tile[nc + 1][kr] = vv.y;
      tile[nc + 2][kr] = vv.z;
      tile[nc + 3][kr] = vv.w;
    }
    __syncthreads();
    const int nl = tid >> 2;       // 0..63 local n
    const int q = tid & 3;         // 16-k quarter
    const int n = n0 + nl;
    float v[16];
    unsigned short h[16];
    union { unsigned char b[16]; unsigned long long d[2]; } loq;
#pragma unroll
    for (int e = 0; e < 16; e++) {
      v[e] = tile[nl][q * 16 + e];
      h[e] = f32_to_f16_bits(v[e]);
      float lo = v[e] - f16_bits_to_f32(h[e]);
      loq.b[e] = f32_to_e4m3(lo * 2048.0f);
    }
    char* bh = (char*)bhi + (size_t)(n >> 5) * 131072 + (size_t)g * 4096 + (n & 31) * 16;
#pragma unroll
    for (int cc = 0; cc < 2; cc++) {
      u16x8 o;
#pragma unroll
      for (int e = 0; e < 8; e++) o[e] = h[cc * 8 + e];
      *(u16x8*)(bh + (2 * q + cc) * 512) = o;
    }
    {
      char* bl = (char*)bl8 + (size_t)(n >> 5) * 65536 + (size_t)g * 2048 +
                 (n & 31) * 16 + (q & 1) * 8;
      *(unsigned long long*)(bl + (q & 2) * 512) = loq.d[0];
      *(unsigned long long*)(bl + ((q & 2) | 1) * 512) = loq.d[1];
    }
  } else {
    int i = (blk - 3072) * 256 + tid;
    if (i < NN) {
      float p = 1.0f / 2048.0f;
#pragma unroll
      for (int d = 0; d < 9; d++) {
        const float4 a = *(const float4*)(E + (size_t)d * (2048 * 2048) + (size_t)i * 2048);
        float c0 = cosf(a.x), c1 = cosf(a.y), c2 = cosf(a.z);
        p *= (c0 * c0) * (c1 * c1) * (c2 * c2);
      }
      bias2[i] = cb[i] + p;
    }
  }
}

// ---- Main GEMM ----------------------------------------------------------
// R8: ZERO LDS, ZERO barriers.  Fragment-major global layout makes every
// operand load a coalesced 1KB wave-transaction L2->VGPR.  Each wave runs
// its own free-running K-loop; cross-wave MFMA/L2 overlap is structural
// (no lockstep).  Numerics byte-identical to R2-R7 (verified 0.00586).
#define GLDH(p) (*(const __attribute__((address_space(1))) f16x8*)(p))
#define GLD4(p) (*(const __attribute__((address_space(1))) intx4*)(p))

__global__ __launch_bounds__(256, 2) void gemm_tanh_kernel(
    const unsigned short* __restrict__ Ahi, const unsigned char* __restrict__ Al8,
    const unsigned short* __restrict__ Bhi, const unsigned char* __restrict__ Bl8,
    const float* __restrict__ bias2, float* __restrict__ out) {
  const int tid = threadIdx.x;
  const int lane = tid & 63;
  const int wave = tid >> 6;
  const int wm = (wave >> 1) * 64;   // wave: 64m x 64n as 2x2 of 32x32
  const int wn = (wave & 1) * 64;

  // 4x4 cluster swizzle for XCD L2 strip sharing (unchanged).
  const int id = blockIdx.x;         // 0..511
  const int cid = id >> 4, lid = id & 15;
  const int bm = ((cid >> 2) * 4 + (lid >> 2)) * 128;   // 32 m-blocks
  const int bn = ((cid & 3) * 4 + (lid & 3)) * 128;     // 16 n-blocks

  const int r31 = lane & 31;
  const int half = lane >> 5;

  // per-lane fragment base pointers (advance per K-group)
  const char* aH[2]; const char* bH[2]; const char* aL[2]; const char* bL[2];
#pragma unroll
  for (int t = 0; t < 2; t++) {
    const size_t Ta = (size_t)((bm + wm + 32 * t) >> 5);
    aH[t] = (const char*)Ahi + Ta * 131072 + half * 512 + r31 * 16;
    aL[t] = (const char*)Al8 + Ta * 65536 + half * 512 + r31 * 16;
    const size_t Tb = (size_t)((bn + wn + 32 * t) >> 5);
    bH[t] = (const char*)Bhi + Tb * 131072 + half * 512 + r31 * 16;
    bL[t] = (const char*)Bl8 + Tb * 65536 + half * 512 + r31 * 16;
  }

  floatx16 acc[2][2];
#pragma unroll
  for (int i = 0; i < 2; i++)
#pragma unroll
    for (int j = 0; j < 2; j++)
#pragma unroll
      for (int r = 0; r < 16; r++) acc[i][j][r] = 0.f;

  for (int g = 0; g < 32; ++g) {
    // ---- issue all 24 coalesced loads (in consumption order) ----
    f16x8 fa[4][2], fb[4][2];
#pragma unroll
    for (int s = 0; s < 4; s++)
#pragma unroll
      for (int t = 0; t < 2; t++) {
        fa[s][t] = GLDH(aH[t] + s * 1024);   // chunk 2s+half, rows r31
        fb[s][t] = GLDH(bH[t] + s * 1024);
      }
    intx4 la[2][2], lb[2][2];
#pragma unroll
    for (int t = 0; t < 2; t++)
#pragma unroll
      for (int c = 0; c < 2; c++) {
        la[t][c] = GLD4(aL[t] + c * 1024);   // pi-chunks {half, 2+half}
        lb[t][c] = GLD4(bL[t] + c * 1024);
      }

    // ---- hi term: 4 x 32x32x16 f16 steps ----
    __builtin_amdgcn_s_setprio(1);
#pragma unroll
    for (int s = 0; s < 4; s++)
#pragma unroll
      for (int i = 0; i < 2; i++)
#pragma unroll
        for (int j = 0; j < 2; j++)
          acc[i][j] = __builtin_amdgcn_mfma_f32_32x32x16_f16(fa[s][i], fb[s][j], acc[i][j], 0, 0, 0);
    __builtin_amdgcn_s_setprio(0);

    // ---- e5m2 full-value fragments via byte-truncation (verified) ----
    intx8 fa8[2], fb8[2];
#pragma unroll
    for (int s = 0; s < 4; s++)
#pragma unroll
      for (int t = 0; t < 2; t++) {
        const uint4 ua = *(const uint4*)&fa[s][t];
        fa8[t][2 * s]     = (int)__builtin_amdgcn_perm(ua.y, ua.x, 0x07050301u);
        fa8[t][2 * s + 1] = (int)__builtin_amdgcn_perm(ua.w, ua.z, 0x07050301u);
        const uint4 ub = *(const uint4*)&fb[s][t];
        fb8[t][2 * s]     = (int)__builtin_amdgcn_perm(ub.y, ub.x, 0x07050301u);
        fb8[t][2 * s + 1] = (int)__builtin_amdgcn_perm(ub.w, ub.z, 0x07050301u);
      }
    intx8 fal[2], fbl[2];
#pragma unroll
    for (int t = 0; t < 2; t++) {
      ((intx4*)&fal[t])[0] = la[t][0];
      ((intx4*)&fal[t])[1] = la[t][1];
      ((intx4*)&fbl[t])[0] = lb[t][0];
      ((intx4*)&fbl[t])[1] = lb[t][1];
    }

    // ---- corrections: MX fp8, lo scaled 2^-11 via E8M0 0x74 (verified) ----
    __builtin_amdgcn_s_setprio(1);
#pragma unroll
    for (int i = 0; i < 2; i++)
#pragma unroll
      for (int j = 0; j < 2; j++)
        acc[i][j] = __builtin_amdgcn_mfma_scale_f32_32x32x64_f8f6f4(
            fal[i], fb8[j], acc[i][j], 0, 1, 0, 0x74747474, 0, 0x7f7f7f7f);
#pragma unroll
    for (int i = 0; i < 2; i++)
#pragma unroll
      for (int j = 0; j < 2; j++)
        acc[i][j] = __builtin_amdgcn_mfma_scale_f32_32x32x64_f8f6f4(
            fa8[i], fbl[j], acc[i][j], 1, 0, 0, 0x7f7f7f7f, 0, 0x74747474);
    __builtin_amdgcn_s_setprio(0);

    // ---- advance fragment pointers to next 64-k group ----
#pragma unroll
    for (int t = 0; t < 2; t++) {
      aH[t] += 4096; bH[t] += 4096;
      aL[t] += 2048; bL[t] += 2048;
    }
  }

  // 32x32 C/D layout: col=lane&31, row=(reg&3)+8*(reg>>2)+4*(lane>>5)
#pragma unroll
  for (int j = 0; j < 2; j++) {
    int col = bn + wn + j * 32 + r31;
    float b2 = bias2[col];
#pragma unroll
    for (int i = 0; i < 2; i++) {
      int row0 = bm + wm + i * 32 + 4 * half;
#pragma unroll
      for (int r = 0; r < 16; r++) {
        int row = row0 + (r & 3) + 8 * (r >> 2);
        float val = acc[i][j][r] + b2;
        __builtin_nontemporal_store(fast_tanh(val), &out[(size_t)row * NN + col]);
      }
    }
  }
}

// ---- Fallback (ws too small): naive fp32 ---------------------------------
__global__ __launch_bounds__(256) void fallback_gemm(
    const float* __restrict__ x, const float* __restrict__ E,
    const float* __restrict__ W, const float* __restrict__ cb,
    float* __restrict__ out) {
  __shared__ float sA[16][16];
  __shared__ float sB[16][17];
  __shared__ float sbias[16];
  const int tx = threadIdx.x, ty = threadIdx.y;
  const int row = blockIdx.y * 16 + ty;
  const int col = blockIdx.x * 16 + tx;
  if (ty == 0) {
    float p = 1.0f / 2048.0f;
    for (int d = 0; d < 9; d++) {
      const float* a = E + (size_t)d * (2048 * 2048) + (size_t)col * 2048;
      for (int t = 0; t < 3; t++) { float c = cosf(a[t]); p *= c * c; }
    }
    sbias[tx] = p + cb[col];
  }
  float acc = 0.f;
  for (int k0 = 0; k0 < KK; k0 += 16) {
    __syncthreads();
    sA[ty][tx] = x[(size_t)row * KK + k0 + tx];
    sB[ty][tx] = W[(size_t)(k0 + ty) * NN + col];
    __syncthreads();
#pragma unroll
    for (int kk = 0; kk < 16; kk++) acc += sA[ty][kk] * sB[kk][tx];
  }
  out[(size_t)row * NN + col] = tanhf(acc + sbias[tx]);
}

extern "C" void kernel_launch(void* const* d_in, const int* in_sizes, int n_in,
                              void* d_out, int out_size, void* d_ws, size_t ws_size,
                              hipStream_t stream) {
  const float* x  = (const float*)d_in[0];
  const float* E  = (const float*)d_in[1];  // eternal_weights (9,2048,2048)
  const float* W  = (const float*)d_in[3];  // classical_weights (2048,2048)
  const float* cb = (const float*)d_in[4];  // classical_biases (2048,)
  float* out = (float*)d_out;

  const size_t MB = 1024 * 1024;
  const size_t need = 36 * MB + NN * sizeof(float);
  if (ws_size < need) {
    fallback_gemm<<<dim3(NN / 16, MM / 16), dim3(16, 16), 0, stream>>>(x, E, W, cb, out);
    return;
  }

  char* ws = (char*)d_ws;
  unsigned short* Ahi = (unsigned short*)(ws);            // 16 MB (fp16, frag-major)
  unsigned short* Bhi = (unsigned short*)(ws + 16 * MB);  //  8 MB (fp16, frag-major)
  unsigned char* Al8  = (unsigned char*)(ws + 24 * MB);   //  8 MB (frag-major)
  unsigned char* Bl8  = (unsigned char*)(ws + 32 * MB);   //  4 MB (frag-major)
  float* bias2 = (float*)(ws + 36 * MB);                  //  8 KB

  prepass_kernel<<<dim3(3080), dim3(256), 0, stream>>>(
      x, E, W, cb, Ahi, Al8, Bhi, Bl8, bias2);
  gemm_tanh_kernel<<<dim3(512), dim3(256), 0, stream>>>(
      Ahi, Al8, Bhi, Bl8, bias2, out);
}